// Round 5
// baseline (91.877 us; speedup 1.0000x reference)
//
#include <hip/hip_runtime.h>
#include <stdint.h>

// Problem constants (from reference)
#define N_AG   8
#define S_SAMP 16
#define TB     8192      // T*B
#define DST    128       // D_STATE
#define E_DIM  64
#define HH_DIM 128

#define RPB    8         // tb-rows per block -> 1024 blocks (4 blocks/CU)
#define HH_PAD 132       // 128-wide LDS rows, stride % 32 == 4
#define E_PAD  68        // 64-wide LDS rows
#define CN_PAD 9         // cn_l inner stride: 9*sl mod 32 covers 16 banks

__device__ __forceinline__ float4 ld4(const float* p) { return *(const float4*)p; }
__device__ __forceinline__ float2 ld2(const float* p) { return *(const float2*)p; }

// ---------------- JAX threefry2x32 (20 rounds) ----------------
__device__ __forceinline__ uint2 tf2x32(uint32_t k0, uint32_t k1,
                                        uint32_t c0, uint32_t c1) {
  uint32_t ks2 = k0 ^ k1 ^ 0x1BD11BDAu;
  uint32_t x0 = c0 + k0, x1 = c1 + k1;
#define TFR(r) { x0 += x1; x1 = (x1 << (r)) | (x1 >> (32 - (r))); x1 ^= x0; }
  TFR(13) TFR(15) TFR(26) TFR(6)
  x0 += k1;  x1 += ks2 + 1u;
  TFR(17) TFR(29) TFR(16) TFR(24)
  x0 += ks2; x1 += k0 + 2u;
  TFR(13) TFR(15) TFR(26) TFR(6)
  x0 += k0;  x1 += k1 + 3u;
  TFR(17) TFR(29) TFR(16) TFR(24)
  x0 += k1;  x1 += ks2 + 4u;
  TFR(13) TFR(15) TFR(26) TFR(6)
  x0 += ks2; x1 += k0 + 5u;
#undef TFR
  return make_uint2(x0, x1);
}

// 128-col GEMM phase: thread = (row rr = tid>>5, cols c0..c0+3), K=128.
// Per thread: 32 ds_read_b128 + 128 global float4 + 512 FMA.
template<int SSTR, int DSTR, int ACT>
__device__ __forceinline__ void gemm128(const float* srcBase,
                                        const float* __restrict__ W,
                                        const float* __restrict__ bias,
                                        float* dstBase, int tid)
{
  const int c0 = (tid & 31) * 4;
  const int rr = tid >> 5;
  const float* s = srcBase + rr * SSTR;
  float ax = 0.f, ay = 0.f, az = 0.f, aw = 0.f;
#pragma unroll 4
  for (int k = 0; k < DST; k += 4) {
    const float4 sv = ld4(s + k);
    const float4 w0 = ld4(&W[(k + 0) * 128 + c0]);
    const float4 w1 = ld4(&W[(k + 1) * 128 + c0]);
    const float4 w2 = ld4(&W[(k + 2) * 128 + c0]);
    const float4 w3 = ld4(&W[(k + 3) * 128 + c0]);
    ax = fmaf(sv.x, w0.x, ax); ay = fmaf(sv.x, w0.y, ay);
    az = fmaf(sv.x, w0.z, az); aw = fmaf(sv.x, w0.w, aw);
    ax = fmaf(sv.y, w1.x, ax); ay = fmaf(sv.y, w1.y, ay);
    az = fmaf(sv.y, w1.z, az); aw = fmaf(sv.y, w1.w, aw);
    ax = fmaf(sv.z, w2.x, ax); ay = fmaf(sv.z, w2.y, ay);
    az = fmaf(sv.z, w2.z, az); aw = fmaf(sv.z, w2.w, aw);
    ax = fmaf(sv.w, w3.x, ax); ay = fmaf(sv.w, w3.y, ay);
    az = fmaf(sv.w, w3.z, az); aw = fmaf(sv.w, w3.w, aw);
  }
  const float4 bv = ld4(&bias[c0]);
  ax += bv.x; ay += bv.y; az += bv.z; aw += bv.w;
  if (ACT == 1) { ax = fmaxf(ax, 0.f); ay = fmaxf(ay, 0.f); az = fmaxf(az, 0.f); aw = fmaxf(aw, 0.f); }
  if (ACT == 2) { ax = fabsf(ax); ay = fabsf(ay); az = fabsf(az); aw = fabsf(aw); }
  *(float4*)(dstBase + rr * DSTR + c0) = make_float4(ax, ay, az, aw);
}

__global__ __launch_bounds__(256)
void alpha_fused3(const float* __restrict__ q_vals,   // (8, 8192)
                  const float* __restrict__ states,   // (8192, 128)
                  const float* __restrict__ hw1_k1, const float* __restrict__ hw1_b1,
                  const float* __restrict__ hw1_k2, const float* __restrict__ hw1_b2,
                  const float* __restrict__ b1_k,   const float* __restrict__ b1_b,
                  const float* __restrict__ hw2_k1, const float* __restrict__ hw2_b1,
                  const float* __restrict__ hw2_k2, const float* __restrict__ hw2_b2,
                  const float* __restrict__ hb2_k1, const float* __restrict__ hb2_b1,
                  const float* __restrict__ hb2_k2, const float* __restrict__ hb2_b2,
                  float* __restrict__ out)            // (8, 8192)
{
  __shared__ float s_lds[RPB][DST];              // 4 KB
  __shared__ float hA[RPB][HH_PAD];              // h1   4.1 KB
  __shared__ float hB[RPB][HH_PAD];              // h2   4.1 KB
  __shared__ float w1l[RPB][HH_PAD];             // |w1| 4.1 KB
  __shared__ float b1l[RPB][E_PAD];              // 2.1 KB
  __shared__ float w2l[RPB][E_PAD];              // 2.1 KB
  __shared__ float hbl[RPB][E_PAD];              // 2.1 KB
  __shared__ float b2l[RPB];
  __shared__ float ql[RPB][N_AG];
  __shared__ float cn_l[RPB][S_SAMP][CN_PAD];    // cn then |y|, 4.6 KB

  const int tid  = threadIdx.x;
  const int row0 = blockIdx.x * RPB;

  // ---- load states (1024 floats = 256 float4) + q ----
  {
    const float4* src = reinterpret_cast<const float4*>(states + (size_t)row0 * DST);
    reinterpret_cast<float4*>(&s_lds[0][0])[tid] = src[tid];
  }
  if (tid < RPB * N_AG) {
    const int rr = tid >> 3, a = tid & 7;
    ql[rr][a] = q_vals[a * TB + row0 + rr];
  }
  __syncthreads();

  // ================= Phase A: h1, h2, [b1|hb], RNG =================
  gemm128<DST, HH_PAD, 1>(&s_lds[0][0], hw1_k1, hw1_b1, &hA[0][0], tid);
  gemm128<DST, HH_PAD, 1>(&s_lds[0][0], hw2_k1, hw2_b1, &hB[0][0], tid);
  {  // merged 64+64-col phase: cols 0..63 -> b1 (no act), 64..127 -> hb (relu)
    const int c0 = (tid & 31) * 4;
    const int rr = tid >> 5;
    const bool isB1 = (c0 < 64);
    const int  cc   = isB1 ? c0 : (c0 - 64);
    const float* W  = isB1 ? b1_k : hb2_k1;
    const float* BI = isB1 ? b1_b : hb2_b1;
    const float* s  = &s_lds[rr][0];
    float ax = 0.f, ay = 0.f, az = 0.f, aw = 0.f;
#pragma unroll 4
    for (int k = 0; k < DST; k += 4) {
      const float4 sv = ld4(s + k);
      const float4 w0 = ld4(&W[(k + 0) * 64 + cc]);
      const float4 w1 = ld4(&W[(k + 1) * 64 + cc]);
      const float4 w2 = ld4(&W[(k + 2) * 64 + cc]);
      const float4 w3 = ld4(&W[(k + 3) * 64 + cc]);
      ax = fmaf(sv.x, w0.x, ax); ay = fmaf(sv.x, w0.y, ay);
      az = fmaf(sv.x, w0.z, az); aw = fmaf(sv.x, w0.w, aw);
      ax = fmaf(sv.y, w1.x, ax); ay = fmaf(sv.y, w1.y, ay);
      az = fmaf(sv.y, w1.z, az); aw = fmaf(sv.y, w1.w, aw);
      ax = fmaf(sv.z, w2.x, ax); ay = fmaf(sv.z, w2.y, ay);
      az = fmaf(sv.z, w2.z, az); aw = fmaf(sv.z, w2.w, aw);
      ax = fmaf(sv.w, w3.x, ax); ay = fmaf(sv.w, w3.y, ay);
      az = fmaf(sv.w, w3.z, az); aw = fmaf(sv.w, w3.w, aw);
    }
    const float4 bv = ld4(&BI[cc]);
    ax += bv.x; ay += bv.y; az += bv.z; aw += bv.w;
    if (isB1) {
      *(float4*)&b1l[rr][cc] = make_float4(ax, ay, az, aw);
    } else {
      *(float4*)&hbl[rr][cc] = make_float4(fmaxf(ax, 0.f), fmaxf(ay, 0.f),
                                           fmaxf(az, 0.f), fmaxf(aw, 0.f));
    }
  }
  if (tid < RPB * S_SAMP) {  // RNG: one (row, sample) per thread (verified chain)
    const int r  = tid >> 4;
    const int sl = tid & 15;
    const uint32_t j = (uint32_t)(row0 + r) * (uint32_t)S_SAMP + (uint32_t)sl;
    uint2 kj  = tf2x32(0u, 42u, 0u, j);       // partitionable split of key(42)
    uint2 sub = tf2x32(kj.x, kj.y, 0u, 1u);   // subkey = split(key_j)[1]
    uint32_t K[N_AG];
#pragma unroll
    for (int i = 0; i < N_AG; ++i) {
      uint2 b = tf2x32(sub.x, sub.y, 0u, (uint32_t)i);
      K[i] = b.x ^ b.y;
    }
    int posa[N_AG];
#pragma unroll
    for (int i = 0; i < N_AG; ++i) {
      int rank = 0;
#pragma unroll
      for (int m = 0; m < N_AG; ++m)
        rank += (K[m] < K[i]) || (K[m] == K[i] && m < i);
      posa[rank] = i;
    }
#pragma unroll
    for (int a = 0; a < N_AG; ++a) {
      const int pa = posa[a];
      float cs = 0.f;
#pragma unroll
      for (int a2 = 0; a2 < N_AG; ++a2)
        cs += (posa[a2] < pa) ? ql[r][a2] : 0.f;
      cn_l[r][sl][a] = cs / (float)max(pa, 1);
    }
  }
  __syncthreads();

  // ================= Phase B: w1, w2, b2 =================
  gemm128<HH_PAD, HH_PAD, 2>(&hA[0][0], hw1_k2, hw1_b2, &w1l[0][0], tid);
  {  // w2 = |h2 @ hw2_k2 + b|: thread = (row rr, 2 cols)
    const int c0 = (tid & 31) * 2;
    const int rr = tid >> 5;
    const float* s = &hB[rr][0];
    float ax = 0.f, ay = 0.f;
#pragma unroll 4
    for (int k = 0; k < DST; k += 4) {
      const float4 sv = ld4(s + k);
      const float2 w0 = ld2(&hw2_k2[(k + 0) * 64 + c0]);
      const float2 w1 = ld2(&hw2_k2[(k + 1) * 64 + c0]);
      const float2 w2 = ld2(&hw2_k2[(k + 2) * 64 + c0]);
      const float2 w3 = ld2(&hw2_k2[(k + 3) * 64 + c0]);
      ax = fmaf(sv.x, w0.x, ax); ay = fmaf(sv.x, w0.y, ay);
      ax = fmaf(sv.y, w1.x, ax); ay = fmaf(sv.y, w1.y, ay);
      ax = fmaf(sv.z, w2.x, ax); ay = fmaf(sv.z, w2.y, ay);
      ax = fmaf(sv.w, w3.x, ax); ay = fmaf(sv.w, w3.y, ay);
    }
    const float2 bv = ld2(&hw2_b2[c0]);
    w2l[rr][c0]     = fabsf(ax + bv.x);
    w2l[rr][c0 + 1] = fabsf(ay + bv.y);
  }
  if (tid < RPB * S_SAMP) {  // b2[r] = hb . hb2_k2 + b : 16-lane partial + shuffle
    const int r  = tid >> 4;
    const int sl = tid & 15;
    float v = hbl[r][sl]      * hb2_k2[sl]
            + hbl[r][sl + 16] * hb2_k2[sl + 16]
            + hbl[r][sl + 32] * hb2_k2[sl + 32]
            + hbl[r][sl + 48] * hb2_k2[sl + 48];
    v += __shfl_down(v, 8, 16); v += __shfl_down(v, 4, 16);
    v += __shfl_down(v, 2, 16); v += __shfl_down(v, 1, 16);
    if (sl == 0) b2l[r] = v + hb2_b2[0];
  }
  __syncthreads();

  // ================= Main: thread = (r, sl, agent-half) =================
  {
    const int sl = tid & 15;
    const int r  = (tid >> 4) & 7;
    const int a0 = (tid >> 7) * 4;    // agents a0..a0+3
    float cn[4], qv[4], y[4];
#pragma unroll
    for (int jj = 0; jj < 4; ++jj) {
      cn[jj] = cn_l[r][sl][a0 + jj];
      qv[jj] = ql[r][a0 + jj];
      y[jj]  = 0.f;
    }
#pragma unroll 4
    for (int e = 0; e < E_DIM; e += 4) {
      const float4 wa  = ld4(&w1l[r][e]);
      const float4 wb  = ld4(&w1l[r][64 + e]);
      const float4 bb  = ld4(&b1l[r][e]);
      const float4 w2v = ld4(&w2l[r][e]);
#pragma unroll
      for (int jj = 0; jj < 4; ++jj) {
        float h;
        h = fmaf(cn[jj], wa.x, fmaf(qv[jj], wb.x, bb.x));
        y[jj] = fmaf((h > 0.f) ? h : (__expf(h) - 1.f), w2v.x, y[jj]);
        h = fmaf(cn[jj], wa.y, fmaf(qv[jj], wb.y, bb.y));
        y[jj] = fmaf((h > 0.f) ? h : (__expf(h) - 1.f), w2v.y, y[jj]);
        h = fmaf(cn[jj], wa.z, fmaf(qv[jj], wb.z, bb.z));
        y[jj] = fmaf((h > 0.f) ? h : (__expf(h) - 1.f), w2v.z, y[jj]);
        h = fmaf(cn[jj], wa.w, fmaf(qv[jj], wb.w, bb.w));
        y[jj] = fmaf((h > 0.f) ? h : (__expf(h) - 1.f), w2v.w, y[jj]);
      }
    }
    const float b2v = b2l[r];
    // overwrite own cn slots with |y| (each thread re-writes exactly the
    // slots it read; the other agent-half touches disjoint slots)
#pragma unroll
    for (int jj = 0; jj < 4; ++jj)
      cn_l[r][sl][a0 + jj] = fabsf(y[jj] + b2v);
  }
  __syncthreads();

  // ---- Reduce over samples; rr = tid&7 so 8 consecutive rows coalesce ----
  if (tid < RPB * N_AG) {
    const int rr = tid & 7, a = tid >> 3;
    float acc = 0.f;
#pragma unroll
    for (int ss = 0; ss < S_SAMP; ++ss) acc += cn_l[rr][ss][a];
    out[a * TB + row0 + rr] = acc * (1.0f / (float)S_SAMP);
  }
}

extern "C" void kernel_launch(void* const* d_in, const int* in_sizes, int n_in,
                              void* d_out, int out_size, void* d_ws, size_t ws_size,
                              hipStream_t stream) {
  const float* q_vals = (const float*)d_in[0];
  const float* states = (const float*)d_in[1];
  const float* hw1_k1 = (const float*)d_in[2];
  const float* hw1_b1 = (const float*)d_in[3];
  const float* hw1_k2 = (const float*)d_in[4];
  const float* hw1_b2 = (const float*)d_in[5];
  const float* b1_k   = (const float*)d_in[6];
  const float* b1_b   = (const float*)d_in[7];
  const float* hw2_k1 = (const float*)d_in[8];
  const float* hw2_b1 = (const float*)d_in[9];
  const float* hw2_k2 = (const float*)d_in[10];
  const float* hw2_b2 = (const float*)d_in[11];
  const float* hb2_k1 = (const float*)d_in[12];
  const float* hb2_b1 = (const float*)d_in[13];
  const float* hb2_k2 = (const float*)d_in[14];
  const float* hb2_b2 = (const float*)d_in[15];
  float* out = (float*)d_out;

  alpha_fused3<<<dim3(TB / RPB), 256, 0, stream>>>(
      q_vals, states, hw1_k1, hw1_b1, hw1_k2, hw1_b2, b1_k, b1_b,
      hw2_k1, hw2_b1, hw2_k2, hw2_b2, hb2_k1, hb2_b1, hb2_k2, hb2_b2, out);
}

// Round 6
// 67.922 us; speedup vs baseline: 1.3527x; 1.3527x over previous
//
#include <hip/hip_runtime.h>
#include <stdint.h>

// Problem constants (from reference)
#define N_AG   8
#define S_SAMP 16
#define TB     8192      // T*B
#define DST    128       // D_STATE
#define E_DIM  64
#define HH_DIM 128

#define RPB    8         // tb-rows per block -> 1024 blocks = 4 blocks/CU
#define H_PAD  132       // 128-wide LDS rows: stride%32==4 -> rows on distinct banks
#define E_PAD  68        // 64-wide LDS rows
#define CN_STR 9         // cn stride: 9*sl mod 32 spreads 16 samples over banks

__device__ __forceinline__ float4 ld4(const float* p) { return *(const float4*)p; }

// ---------------- JAX threefry2x32 (20 rounds) ----------------
__device__ __forceinline__ uint2 tf2x32(uint32_t k0, uint32_t k1,
                                        uint32_t c0, uint32_t c1) {
  uint32_t ks2 = k0 ^ k1 ^ 0x1BD11BDAu;
  uint32_t x0 = c0 + k0, x1 = c1 + k1;
#define TFR(r) { x0 += x1; x1 = (x1 << (r)) | (x1 >> (32 - (r))); x1 ^= x0; }
  TFR(13) TFR(15) TFR(26) TFR(6)
  x0 += k1;  x1 += ks2 + 1u;
  TFR(17) TFR(29) TFR(16) TFR(24)
  x0 += ks2; x1 += k0 + 2u;
  TFR(13) TFR(15) TFR(26) TFR(6)
  x0 += k0;  x1 += k1 + 3u;
  TFR(17) TFR(29) TFR(16) TFR(24)
  x0 += k1;  x1 += ks2 + 4u;
  TFR(13) TFR(15) TFR(26) TFR(6)
  x0 += ks2; x1 += k0 + 5u;
#undef TFR
  return make_uint2(x0, x1);
}

// 128-col GEMM phase (R4-proven shape): c = tid&127 (1 col), g = tid>>7
// (2 row-groups x 4 rows). Weights: scalar dword, coalesced, redundancy 2.
// States: b128 broadcast (uniform addr per wave) -> conflict-free.
template<int ACT>   // 0=none 1=relu 2=abs
__device__ __forceinline__ void phase128(const float* src, int sstr,
                                         const float* __restrict__ W,
                                         const float* __restrict__ bias,
                                         float* dst, int dstr, int tid)
{
  const int c = tid & 127, g = tid >> 7;
  const float* s0 = src + (g * 4 + 0) * sstr;
  const float* s1 = src + (g * 4 + 1) * sstr;
  const float* s2 = src + (g * 4 + 2) * sstr;
  const float* s3 = src + (g * 4 + 3) * sstr;
  float a0 = 0.f, a1 = 0.f, a2 = 0.f, a3 = 0.f;
#pragma unroll 4
  for (int k = 0; k < DST; k += 4) {
    const float w0 = W[(k + 0) * 128 + c];
    const float w1 = W[(k + 1) * 128 + c];
    const float w2 = W[(k + 2) * 128 + c];
    const float w3 = W[(k + 3) * 128 + c];
    float4 v;
    v = ld4(s0 + k);
    a0 = fmaf(v.x, w0, a0); a0 = fmaf(v.y, w1, a0);
    a0 = fmaf(v.z, w2, a0); a0 = fmaf(v.w, w3, a0);
    v = ld4(s1 + k);
    a1 = fmaf(v.x, w0, a1); a1 = fmaf(v.y, w1, a1);
    a1 = fmaf(v.z, w2, a1); a1 = fmaf(v.w, w3, a1);
    v = ld4(s2 + k);
    a2 = fmaf(v.x, w0, a2); a2 = fmaf(v.y, w1, a2);
    a2 = fmaf(v.z, w2, a2); a2 = fmaf(v.w, w3, a2);
    v = ld4(s3 + k);
    a3 = fmaf(v.x, w0, a3); a3 = fmaf(v.y, w1, a3);
    a3 = fmaf(v.z, w2, a3); a3 = fmaf(v.w, w3, a3);
  }
  const float b = bias[c];
  a0 += b; a1 += b; a2 += b; a3 += b;
  if (ACT == 1) { a0 = fmaxf(a0, 0.f); a1 = fmaxf(a1, 0.f);
                  a2 = fmaxf(a2, 0.f); a3 = fmaxf(a3, 0.f); }
  if (ACT == 2) { a0 = fabsf(a0); a1 = fabsf(a1); a2 = fabsf(a2); a3 = fabsf(a3); }
  dst[(g * 4 + 0) * dstr + c] = a0;
  dst[(g * 4 + 1) * dstr + c] = a1;
  dst[(g * 4 + 2) * dstr + c] = a2;
  dst[(g * 4 + 3) * dstr + c] = a3;
}

__global__ __launch_bounds__(256)
void alpha_fused4(const float* __restrict__ q_vals,   // (8, 8192)
                  const float* __restrict__ states,   // (8192, 128)
                  const float* __restrict__ hw1_k1, const float* __restrict__ hw1_b1,
                  const float* __restrict__ hw1_k2, const float* __restrict__ hw1_b2,
                  const float* __restrict__ b1_k,   const float* __restrict__ b1_b,
                  const float* __restrict__ hw2_k1, const float* __restrict__ hw2_b1,
                  const float* __restrict__ hw2_k2, const float* __restrict__ hw2_b2,
                  const float* __restrict__ hb2_k1, const float* __restrict__ hb2_b1,
                  const float* __restrict__ hb2_k2, const float* __restrict__ hb2_b2,
                  float* __restrict__ out)            // (8, 8192)
{
  __shared__ float s_lds[RPB][DST];              // 4 KB
  __shared__ float h1l[RPB][H_PAD];              // 4.2 KB
  __shared__ float h2l[RPB][H_PAD];              // 4.2 KB
  __shared__ float w1l[RPB][H_PAD];              // 4.2 KB
  __shared__ float b1l[RPB][E_PAD];              // 2.2 KB
  __shared__ float w2l[RPB][E_PAD];              // 2.2 KB
  __shared__ float hbl[RPB][E_PAD];              // 2.2 KB
  __shared__ float b2l[RPB];
  __shared__ float ql[RPB][N_AG];
  __shared__ float cn_l[RPB][S_SAMP][CN_STR];    // cn then |y|, 4.6 KB

  const int tid  = threadIdx.x;
  const int row0 = blockIdx.x * RPB;

  // ---- load states (1024 floats = 256 float4) + q ----
  {
    const float4* src = reinterpret_cast<const float4*>(states + (size_t)row0 * DST);
    reinterpret_cast<float4*>(&s_lds[0][0])[tid] = src[tid];
  }
  if (tid < RPB * N_AG) {
    const int rr = tid >> 3, a = tid & 7;
    ql[rr][a] = q_vals[a * TB + row0 + rr];
  }
  __syncthreads();

  // ============ Phase 1: h1, h2, merged [b1|hb], RNG ============
  phase128<1>(&s_lds[0][0], DST, hw1_k1, hw1_b1, &h1l[0][0], H_PAD, tid);
  phase128<1>(&s_lds[0][0], DST, hw2_k1, hw2_b1, &h2l[0][0], H_PAD, tid);
  {  // merged 64+64: virtual cols 0..63 -> b1 (no act), 64..127 -> hb (relu)
    const int c = tid & 127, g = tid >> 7;
    const bool lo = (c < 64);
    const int  cc = c & 63;
    const float* W  = lo ? b1_k : hb2_k1;
    const float* BI = lo ? b1_b : hb2_b1;
    float*      dst = lo ? &b1l[0][0] : &hbl[0][0];
    const float* s0 = &s_lds[g * 4 + 0][0];
    const float* s1 = &s_lds[g * 4 + 1][0];
    const float* s2 = &s_lds[g * 4 + 2][0];
    const float* s3 = &s_lds[g * 4 + 3][0];
    float a0 = 0.f, a1 = 0.f, a2 = 0.f, a3 = 0.f;
#pragma unroll 4
    for (int k = 0; k < DST; k += 4) {
      const float w0 = W[(k + 0) * 64 + cc];
      const float w1 = W[(k + 1) * 64 + cc];
      const float w2 = W[(k + 2) * 64 + cc];
      const float w3 = W[(k + 3) * 64 + cc];
      float4 v;
      v = ld4(s0 + k);
      a0 = fmaf(v.x, w0, a0); a0 = fmaf(v.y, w1, a0);
      a0 = fmaf(v.z, w2, a0); a0 = fmaf(v.w, w3, a0);
      v = ld4(s1 + k);
      a1 = fmaf(v.x, w0, a1); a1 = fmaf(v.y, w1, a1);
      a1 = fmaf(v.z, w2, a1); a1 = fmaf(v.w, w3, a1);
      v = ld4(s2 + k);
      a2 = fmaf(v.x, w0, a2); a2 = fmaf(v.y, w1, a2);
      a2 = fmaf(v.z, w2, a2); a2 = fmaf(v.w, w3, a2);
      v = ld4(s3 + k);
      a3 = fmaf(v.x, w0, a3); a3 = fmaf(v.y, w1, a3);
      a3 = fmaf(v.z, w2, a3); a3 = fmaf(v.w, w3, a3);
    }
    const float b = BI[cc];
    a0 += b; a1 += b; a2 += b; a3 += b;
    if (!lo) { a0 = fmaxf(a0, 0.f); a1 = fmaxf(a1, 0.f);
               a2 = fmaxf(a2, 0.f); a3 = fmaxf(a3, 0.f); }
    dst[(g * 4 + 0) * E_PAD + cc] = a0;
    dst[(g * 4 + 1) * E_PAD + cc] = a1;
    dst[(g * 4 + 2) * E_PAD + cc] = a2;
    dst[(g * 4 + 3) * E_PAD + cc] = a3;
  }
  if (tid < RPB * S_SAMP) {  // RNG: one (row, sample) per thread (verified chain)
    const int r  = tid >> 4;
    const int sl = tid & 15;
    const uint32_t j = (uint32_t)(row0 + r) * (uint32_t)S_SAMP + (uint32_t)sl;
    uint2 kj  = tf2x32(0u, 42u, 0u, j);       // partitionable split of key(42)
    uint2 sub = tf2x32(kj.x, kj.y, 0u, 1u);   // subkey = split(key_j)[1]
    uint32_t K[N_AG];
#pragma unroll
    for (int i = 0; i < N_AG; ++i) {
      uint2 b = tf2x32(sub.x, sub.y, 0u, (uint32_t)i);
      K[i] = b.x ^ b.y;
    }
    int posa[N_AG];
#pragma unroll
    for (int i = 0; i < N_AG; ++i) {
      int rank = 0;
#pragma unroll
      for (int m = 0; m < N_AG; ++m)
        rank += (K[m] < K[i]) || (K[m] == K[i] && m < i);
      posa[rank] = i;
    }
#pragma unroll
    for (int a = 0; a < N_AG; ++a) {
      const int pa = posa[a];
      float cs = 0.f;
#pragma unroll
      for (int a2 = 0; a2 < N_AG; ++a2)
        cs += (posa[a2] < pa) ? ql[r][a2] : 0.f;
      cn_l[r][sl][a] = cs / (float)max(pa, 1);
    }
  }
  __syncthreads();

  // ============ Phase 2: w1, w2, b2 ============
  phase128<2>(&h1l[0][0], H_PAD, hw1_k2, hw1_b2, &w1l[0][0], H_PAD, tid);
  {  // w2 = |h2 @ hw2_k2 + b|: c = tid&63, g = tid>>6 -> 4 groups x 2 rows
    const int c = tid & 63, g = tid >> 6;
    const float* s0 = &h2l[g * 2 + 0][0];
    const float* s1 = &h2l[g * 2 + 1][0];
    float a0 = 0.f, a1 = 0.f;
#pragma unroll 4
    for (int k = 0; k < DST; k += 4) {
      const float w0 = hw2_k2[(k + 0) * 64 + c];
      const float w1 = hw2_k2[(k + 1) * 64 + c];
      const float w2 = hw2_k2[(k + 2) * 64 + c];
      const float w3 = hw2_k2[(k + 3) * 64 + c];
      float4 v;
      v = ld4(s0 + k);
      a0 = fmaf(v.x, w0, a0); a0 = fmaf(v.y, w1, a0);
      a0 = fmaf(v.z, w2, a0); a0 = fmaf(v.w, w3, a0);
      v = ld4(s1 + k);
      a1 = fmaf(v.x, w0, a1); a1 = fmaf(v.y, w1, a1);
      a1 = fmaf(v.z, w2, a1); a1 = fmaf(v.w, w3, a1);
    }
    const float b = hw2_b2[c];
    w2l[g * 2 + 0][c] = fabsf(a0 + b);
    w2l[g * 2 + 1][c] = fabsf(a1 + b);
  }
  if (tid < RPB * S_SAMP) {  // b2[r] = hb . hb2_k2 + b (16-lane partial + shuffle)
    const int r  = tid >> 4;
    const int sl = tid & 15;
    float v = hbl[r][sl]      * hb2_k2[sl]
            + hbl[r][sl + 16] * hb2_k2[sl + 16]
            + hbl[r][sl + 32] * hb2_k2[sl + 32]
            + hbl[r][sl + 48] * hb2_k2[sl + 48];
    v += __shfl_down(v, 8, 16); v += __shfl_down(v, 4, 16);
    v += __shfl_down(v, 2, 16); v += __shfl_down(v, 1, 16);
    if (sl == 0) b2l[r] = v + hb2_b2[0];
  }
  __syncthreads();

  // ============ Main: thread = (r, sl, agent-half), all 256 active ============
  {
    const int sl = tid & 15;
    const int r  = (tid >> 4) & 7;
    const int a0 = (tid >> 7) * 4;    // agents a0..a0+3
    float cn[4], qv[4], y[4];
#pragma unroll
    for (int jj = 0; jj < 4; ++jj) {
      cn[jj] = cn_l[r][sl][a0 + jj];
      qv[jj] = ql[r][a0 + jj];
      y[jj]  = 0.f;
    }
#pragma unroll 4
    for (int e = 0; e < E_DIM; e += 4) {
      const float4 wa  = ld4(&w1l[r][e]);
      const float4 wb  = ld4(&w1l[r][64 + e]);
      const float4 bb  = ld4(&b1l[r][e]);
      const float4 w2v = ld4(&w2l[r][e]);
#pragma unroll
      for (int jj = 0; jj < 4; ++jj) {
        float h;
        h = fmaf(cn[jj], wa.x, fmaf(qv[jj], wb.x, bb.x));
        y[jj] = fmaf((h > 0.f) ? h : (__expf(h) - 1.f), w2v.x, y[jj]);
        h = fmaf(cn[jj], wa.y, fmaf(qv[jj], wb.y, bb.y));
        y[jj] = fmaf((h > 0.f) ? h : (__expf(h) - 1.f), w2v.y, y[jj]);
        h = fmaf(cn[jj], wa.z, fmaf(qv[jj], wb.z, bb.z));
        y[jj] = fmaf((h > 0.f) ? h : (__expf(h) - 1.f), w2v.z, y[jj]);
        h = fmaf(cn[jj], wa.w, fmaf(qv[jj], wb.w, bb.w));
        y[jj] = fmaf((h > 0.f) ? h : (__expf(h) - 1.f), w2v.w, y[jj]);
      }
    }
    const float b2v = b2l[r];
    // overwrite own cn slots with |y| (each thread re-writes exactly the
    // slots it read; the other agent-half touches disjoint slots)
#pragma unroll
    for (int jj = 0; jj < 4; ++jj)
      cn_l[r][sl][a0 + jj] = fabsf(y[jj] + b2v);
  }
  __syncthreads();

  // ---- Reduce over samples; rr = tid&7 so 8 consecutive rows coalesce ----
  if (tid < RPB * N_AG) {
    const int rr = tid & 7, a = tid >> 3;
    float acc = 0.f;
#pragma unroll
    for (int ss = 0; ss < S_SAMP; ++ss) acc += cn_l[rr][ss][a];
    out[a * TB + row0 + rr] = acc * (1.0f / (float)S_SAMP);
  }
}

extern "C" void kernel_launch(void* const* d_in, const int* in_sizes, int n_in,
                              void* d_out, int out_size, void* d_ws, size_t ws_size,
                              hipStream_t stream) {
  const float* q_vals = (const float*)d_in[0];
  const float* states = (const float*)d_in[1];
  const float* hw1_k1 = (const float*)d_in[2];
  const float* hw1_b1 = (const float*)d_in[3];
  const float* hw1_k2 = (const float*)d_in[4];
  const float* hw1_b2 = (const float*)d_in[5];
  const float* b1_k   = (const float*)d_in[6];
  const float* b1_b   = (const float*)d_in[7];
  const float* hw2_k1 = (const float*)d_in[8];
  const float* hw2_b1 = (const float*)d_in[9];
  const float* hw2_k2 = (const float*)d_in[10];
  const float* hw2_b2 = (const float*)d_in[11];
  const float* hb2_k1 = (const float*)d_in[12];
  const float* hb2_b1 = (const float*)d_in[13];
  const float* hb2_k2 = (const float*)d_in[14];
  const float* hb2_b2 = (const float*)d_in[15];
  float* out = (float*)d_out;

  alpha_fused4<<<dim3(TB / RPB), 256, 0, stream>>>(
      q_vals, states, hw1_k1, hw1_b1, hw1_k2, hw1_b2, b1_k, b1_b,
      hw2_k1, hw2_b1, hw2_k2, hw2_b2, hb2_k1, hb2_b1, hb2_k2, hb2_b2, out);
}